// Round 4
// baseline (359.558 us; speedup 1.0000x reference)
//
#include <hip/hip_runtime.h>
#include <math.h>

#define HW 96
#define N_VOX (96*96*96)        // 884736 voxels per volume
#define NVOL 8                  // 4 pred + 4 target volumes
#define NEL (4*N_VOX)           // 3538944 elements in pred/target
#define PLANE (96*96)           // 9216

// tile geometry for local CCL: full d-span x TW x TH
#define TW 8
#define TH 8
#define TILES_W (96/TW)         // 12
#define TILES_H (96/TH)         // 12
#define TILE_VOX (96*TW*TH)     // 6144

#define NBPLANES 11             // interior tile boundaries per axis
#define NFACES (2*NBPLANES)     // 22 faces per volume
#define HT_SIZE 4096            // LDS hash set entries (32 KB)

// ---------------------------------------------------------------------------
__device__ __forceinline__ bool fg_at(const float* __restrict__ pred,
                                      const float* __restrict__ targ,
                                      int v, int j) {
    if (v < 4) {
        float x = pred[(size_t)v * N_VOX + j];
        float p = 1.0f / (1.0f + expf(-x));
        return p > 0.5f;
    } else {
        return targ[(size_t)(v - 4) * N_VOX + j] > 0.5f;
    }
}

// ---------------------------------------------------------------------------
// focal loss partial sum
__global__ void focal_kernel(const float* __restrict__ x,
                             const float* __restrict__ t,
                             float* __restrict__ acc, int n) {
    int idx = blockIdx.x * blockDim.x + threadIdx.x;
    int stride = gridDim.x * blockDim.x;
    float sum = 0.0f;
    for (int i = idx; i < n; i += stride) {
        float xv = x[i];
        float tv = t[i];
        float p  = 1.0f / (1.0f + expf(-xv));
        float pt = (tv == 1.0f) ? p : 1.0f - p;
        float sp  = fmaxf(xv, 0.0f) + log1pf(expf(-fabsf(xv)));
        float bce = sp - xv * tv;
        float at  = (tv == 1.0f) ? 0.25f : 0.75f;
        float om  = 1.0f - pt;
        sum += at * om * om * bce;
    }
    __shared__ float sdata[256];
    sdata[threadIdx.x] = sum;
    __syncthreads();
    for (int s = blockDim.x >> 1; s > 0; s >>= 1) {
        if (threadIdx.x < s) sdata[threadIdx.x] += sdata[threadIdx.x + s];
        __syncthreads();
    }
    if (threadIdx.x == 0) atomicAdd(acc, sdata[0]);
}

// ---------------------------------------------------------------------------
// lock-free union-find merge on GLOBAL labels (Playne-Hawick). Labels only
// decrease; all linking via device-scope atomicMin -> stale plain reads only
// cause retries, never bad unions.
__device__ __forceinline__ void merge_labels(int* __restrict__ L, int l1, int l2) {
    while (l1 != l2 && l1 != L[l1]) l1 = L[l1];
    while (l1 != l2 && l2 != L[l2]) l2 = L[l2];
    while (l1 != l2) {
        if (l1 < l2) { int tmp = l1; l1 = l2; l2 = tmp; }  // l1 > l2
        int l3 = atomicMin(&L[l1], l2);
        l1 = (l3 == l1) ? l2 : l3;
    }
}

__device__ __forceinline__ int find_root(const int* __restrict__ L, int x) {
    while (L[x] != x) x = L[x];
    return x;
}

// same on LDS labels
__device__ __forceinline__ void merge_local(int* lab, int l1, int l2) {
    while (l1 != l2 && l1 != lab[l1]) l1 = lab[l1];
    while (l1 != l2 && l2 != lab[l2]) l2 = lab[l2];
    while (l1 != l2) {
        if (l1 < l2) { int tmp = l1; l1 = l2; l2 = tmp; }
        int l3 = atomicMin(&lab[l1], l2);
        l1 = (l3 == l1) ? l2 : l3;
    }
}

// ---------------------------------------------------------------------------
// Phase 1: per-tile CCL in LDS; write resolved tile-roots (global indices)
// for fg voxels, -1 for bg voxels (so later phases never touch pred/targ).
__global__ __launch_bounds__(256) void ccl_local(const float* __restrict__ pred,
                                                 const float* __restrict__ targ,
                                                 int* __restrict__ Lg, int vbase) {
    __shared__ int lab[TILE_VOX];
    __shared__ unsigned char fgs[TILE_VOX];
    int vloc = blockIdx.y;
    int v = vbase + vloc;
    int tile = blockIdx.x;                 // 0..143
    int w0 = (tile % TILES_W) * TW;
    int h0 = (tile / TILES_W) * TH;
    int* Lvg = Lg + (size_t)vloc * N_VOX;

    for (int i = threadIdx.x; i < TILE_VOX; i += blockDim.x) {
        int d = i % 96, lw = (i / 96) % TW, lh = i / (96 * TW);
        int j = (h0 + lh) * PLANE + (w0 + lw) * 96 + d;
        bool f = fg_at(pred, targ, v, j);
        fgs[i] = f ? 1 : 0;
        lab[i] = i;
    }
    __syncthreads();

    for (int i = threadIdx.x; i < TILE_VOX; i += blockDim.x) {
        if (!fgs[i]) continue;
        int d = i % 96, lw = (i / 96) % TW, lh = i / (96 * TW);
        if (d  < 95     && fgs[i + 1])       merge_local(lab, i, i + 1);
        if (lw < TW - 1 && fgs[i + 96])      merge_local(lab, i, i + 96);
        if (lh < TH - 1 && fgs[i + 96*TW])   merge_local(lab, i, i + 96*TW);
    }
    __syncthreads();

    for (int i = threadIdx.x; i < TILE_VOX; i += blockDim.x) {
        int d  = i % 96, lw = (i / 96) % TW, lh = i / (96 * TW);
        int j  = (h0 + lh) * PLANE + (w0 + lw) * 96 + d;
        int val = -1;
        if (fgs[i]) {
            int r = i;
            while (lab[r] != r) r = lab[r];
            int rd = r % 96, rw = (r / 96) % TW, rh = r / (96 * TW);
            val = (h0 + rh) * PLANE + (w0 + rw) * 96 + rd;  // <= j, order-preserving
        }
        Lvg[j] = val;
    }
}

// ---------------------------------------------------------------------------
// Phase 2: one block per (face, volume). Resolve edge endpoints to current
// roots, dedupe root-pairs via an LDS hash set, merge only unique pairs.
// Missed dedup under racing roots = redundant merge (harmless); exact key
// compare means no false skips.
__global__ __launch_bounds__(256) void ccl_boundary(int* __restrict__ Lg) {
    __shared__ unsigned long long ht[HT_SIZE];
    for (int i = threadIdx.x; i < HT_SIZE; i += 256) ht[i] = ~0ull;
    __syncthreads();

    int face = blockIdx.x;                 // 0..21
    int vloc = blockIdx.y;
    int* Lv = Lg + (size_t)vloc * N_VOX;
    bool wface = face < NBPLANES;
    int p = wface ? face : face - NBPLANES;

    for (int e = threadIdx.x; e < PLANE; e += 256) {
        int j, jn;
        if (wface) {                       // w-faces: w in {8,16,...,88}
            int h = e / 96, d = e % 96;
            int w = (p + 1) * TW;
            j  = h * PLANE + w * 96 + d;
            jn = j - 96;
        } else {                           // h-faces: h in {8,16,...,88}
            int w = e / 96, d = e % 96;
            int h = (p + 1) * TH;
            j  = h * PLANE + w * 96 + d;
            jn = j - PLANE;
        }
        int a = Lv[j], b = Lv[jn];
        if (a < 0 || b < 0) continue;      // bg on either side
        a = find_root(Lv, a);
        b = find_root(Lv, b);
        if (a == b) continue;
        int rmin = a < b ? a : b;
        int rmax = a < b ? b : a;
        unsigned long long key = ((unsigned long long)rmin << 20) | (unsigned)rmax;
        unsigned long long hsh = (key ^ (key >> 29)) * 0x9E3779B97F4A7C15ull;
        unsigned slot = (unsigned)(hsh >> 52) & (HT_SIZE - 1);
        bool do_merge = false;
        for (int probes = 0; probes < HT_SIZE; probes++) {
            unsigned long long prev = atomicCAS(&ht[slot], ~0ull, key);
            if (prev == ~0ull) { do_merge = true; break; }   // we inserted
            if (prev == key)   { break; }                    // duplicate
            slot = (slot + 1) & (HT_SIZE - 1);
            if (probes == HT_SIZE - 1) do_merge = true;      // table full: merge anyway
        }
        if (do_merge) merge_labels(Lv, rmin, rmax);
    }
}

// ---------------------------------------------------------------------------
// Phase 3: count roots (L[j]==j) per volume; int4 loads + block reduction.
__global__ __launch_bounds__(256) void ccl_count(const int* __restrict__ L,
                                                 int* __restrict__ counts, int vbase) {
    int vloc = blockIdx.y;
    const int4* Lv = (const int4*)(L + (size_t)vloc * N_VOX);
    int t = blockIdx.x * blockDim.x + threadIdx.x;   // int4 index
    int cnt = 0;
    if (t < N_VOX / 4) {
        int4 q = Lv[t];
        int b = t * 4;
        cnt = (q.x == b) + (q.y == b + 1) + (q.z == b + 2) + (q.w == b + 3);
    }
    __shared__ int s[256];
    s[threadIdx.x] = cnt;
    __syncthreads();
    for (int st = 128; st > 0; st >>= 1) {
        if (threadIdx.x < st) s[threadIdx.x] += s[threadIdx.x + st];
        __syncthreads();
    }
    if (threadIdx.x == 0 && s[0]) atomicAdd(&counts[vbase + vloc], s[0]);
}

// ---------------------------------------------------------------------------
__global__ void finalize_kernel(const float* __restrict__ acc,
                                const int* __restrict__ counts,
                                float* __restrict__ out) {
    float focal = acc[0] / (float)NEL;
    float dp0 = 0.5f * (float)(counts[0] + counts[2]);
    float dp1 = 0.5f * (float)(counts[1] + counts[3]);
    float dt0 = 0.5f * (float)(counts[4] + counts[6]);
    float dt1 = 0.5f * (float)(counts[5] + counts[7]);
    float topo = 0.5f * (fabsf(dp0 - dt0) + fabsf(dp1 - dt1));
    out[0] = focal + 0.1f * topo;
}

// ---------------------------------------------------------------------------
extern "C" void kernel_launch(void* const* d_in, const int* in_sizes, int n_in,
                              void* d_out, int out_size, void* d_ws, size_t ws_size,
                              hipStream_t stream) {
    const float* pred = (const float*)d_in[0];
    const float* targ = (const float*)d_in[1];
    float* out = (float*)d_out;

    float* acc    = (float*)d_ws;
    int*   counts = (int*)((char*)d_ws + 64);
    int*   labels = (int*)((char*)d_ws + 256);

    size_t avail_ints = (ws_size > 256) ? (ws_size - 256) / 4 : 0;
    int vols_per_pass = (int)(avail_ints / N_VOX);
    if (vols_per_pass > NVOL) vols_per_pass = NVOL;
    if (vols_per_pass < 1) vols_per_pass = 1;

    hipMemsetAsync(d_ws, 0, 256, stream);

    focal_kernel<<<1024, 256, 0, stream>>>(pred, targ, acc, NEL);

    for (int vbase = 0; vbase < NVOL; vbase += vols_per_pass) {
        int nv = NVOL - vbase;
        if (nv > vols_per_pass) nv = vols_per_pass;
        dim3 tgrid(TILES_W * TILES_H, nv);
        ccl_local<<<tgrid, dim3(256), 0, stream>>>(pred, targ, labels, vbase);
        dim3 bgrid(NFACES, nv);
        ccl_boundary<<<bgrid, dim3(256), 0, stream>>>(labels);
        dim3 cgrid((N_VOX / 4 + 255) / 256, nv);
        ccl_count<<<cgrid, dim3(256), 0, stream>>>(labels, counts, vbase);
    }

    finalize_kernel<<<1, 1, 0, stream>>>(acc, counts, out);
}

// Round 5
// 298.632 us; speedup vs baseline: 1.2040x; 1.2040x over previous
//
#include <hip/hip_runtime.h>
#include <math.h>

#define N_VOX (96*96*96)        // 884736 voxels per volume
#define NVOL 8                  // 4 pred + 4 target volumes
#define NEL (4*N_VOX)           // 3538944 elements in pred/target
#define PLANE (96*96)           // 9216

// tile geometry for local CCL: full d-span x TW x TH
#define TW 8
#define TH 8
#define TILES_W 12
#define TILES_H 12
#define TILE_VOX (96*TW*TH)     // 6144

#define NBPLANES 11             // interior tile boundaries per axis
#define BOUND_VOX (2*NBPLANES*PLANE)    // 202752 edges/volume; 792*256 exactly
#define HT_SIZE 512             // per-block LDS dedup entries (4 KB)

// ---------------------------------------------------------------------------
// find with path compression. Writes via atomicMin only -> labels stay
// monotonically decreasing (the invariant all correctness rests on).
__device__ __forceinline__ int find_root_compress(int* __restrict__ L, int x) {
    int r = x;
    int p = L[r];
    while (p != r) { r = p; p = L[r]; }
    if (r != x) atomicMin(&L[x], r);
    return r;
}

// atomicMin union-find merge; returns # of destroyed self-loops (= union
// events). A self-loop destruction is observed by exactly one thread
// (atomicMin returns the old value atomically), and labels never return to
// self once linked, so summing these over all merges gives exactly
// (#initial roots - #final roots) per volume.
__device__ __forceinline__ int merge_count(int* __restrict__ L, int l1, int l2) {
    int ev = 0;
    while (l1 != l2) {
        if (l1 < l2) { int t = l1; l1 = l2; l2 = t; }   // l1 > l2
        int l3 = atomicMin(&L[l1], l2);
        if (l3 == l1) { ev++; l1 = l2; }                // destroyed a root
        else l1 = l3;
    }
    return ev;
}

// same merge on LDS labels (no event counting needed locally)
__device__ __forceinline__ void merge_local(int* lab, int l1, int l2) {
    while (l1 != l2 && l1 != lab[l1]) l1 = lab[l1];
    while (l1 != l2 && l2 != lab[l2]) l2 = lab[l2];
    while (l1 != l2) {
        if (l1 < l2) { int t = l1; l1 = l2; l2 = t; }
        int l3 = atomicMin(&lab[l1], l2);
        l1 = (l3 == l1) ? l2 : l3;
    }
}

// ---------------------------------------------------------------------------
// Phase 1: per-tile CCL in LDS. Writes resolved tile-roots (global indices)
// for fg voxels, -1 for bg. Also: (a) pred blocks (v<4) fuse the focal-loss
// partial sum (they already read pred; add the matching targ element),
// (b) counts local roots per tile into rootcnt[v].
__global__ __launch_bounds__(256) void ccl_local(const float* __restrict__ pred,
                                                 const float* __restrict__ targ,
                                                 int* __restrict__ Lg,
                                                 int* __restrict__ rootcnt,
                                                 float* __restrict__ acc,
                                                 int vbase) {
    __shared__ int lab[TILE_VOX];
    __shared__ unsigned char fgs[TILE_VOX];
    __shared__ float fred[256];
    __shared__ int   ired[256];

    int vloc = blockIdx.y;
    int v = vbase + vloc;
    int tile = blockIdx.x;                 // 0..143
    int w0 = (tile % TILES_W) * TW;
    int h0 = (tile / TILES_W) * TH;
    int* Lvg = Lg + (size_t)vloc * N_VOX;

    float fsum = 0.0f;
    for (int i = threadIdx.x; i < TILE_VOX; i += 256) {
        int d = i % 96, lw = (i / 96) % TW, lh = i / (96 * TW);
        int j = (h0 + lh) * PLANE + (w0 + lw) * 96 + d;
        bool f;
        if (v < 4) {
            float xv = pred[(size_t)v * N_VOX + j];
            float tv = targ[(size_t)v * N_VOX + j];
            float p  = 1.0f / (1.0f + expf(-xv));
            f = p > 0.5f;
            // focal partial (each (v,j) visited exactly once across tiles)
            float pt  = (tv == 1.0f) ? p : 1.0f - p;
            float sp  = fmaxf(xv, 0.0f) + log1pf(expf(-fabsf(xv)));
            float bce = sp - xv * tv;
            float at  = (tv == 1.0f) ? 0.25f : 0.75f;
            float om  = 1.0f - pt;
            fsum += at * om * om * bce;
        } else {
            f = targ[(size_t)(v - 4) * N_VOX + j] > 0.5f;
        }
        fgs[i] = f ? 1 : 0;
        lab[i] = i;
    }
    __syncthreads();

    // intra-tile merges (3 forward edges per fg voxel), LDS atomics only
    for (int i = threadIdx.x; i < TILE_VOX; i += 256) {
        if (!fgs[i]) continue;
        int d = i % 96, lw = (i / 96) % TW, lh = i / (96 * TW);
        if (d  < 95     && fgs[i + 1])       merge_local(lab, i, i + 1);
        if (lw < TW - 1 && fgs[i + 96])      merge_local(lab, i, i + 96);
        if (lh < TH - 1 && fgs[i + 96*TW])   merge_local(lab, i, i + 96*TW);
    }
    __syncthreads();

    // resolve to local root, convert to global index, store; count roots
    int rc = 0;
    for (int i = threadIdx.x; i < TILE_VOX; i += 256) {
        int d  = i % 96, lw = (i / 96) % TW, lh = i / (96 * TW);
        int j  = (h0 + lh) * PLANE + (w0 + lw) * 96 + d;
        int val = -1;
        if (fgs[i]) {
            int r = i;
            while (lab[r] != r) r = lab[r];
            if (r == i) rc++;
            int rd = r % 96, rw = (r / 96) % TW, rh = r / (96 * TW);
            val = (h0 + rh) * PLANE + (w0 + rw) * 96 + rd;  // <= j, order-preserving
        }
        Lvg[j] = val;
    }

    // block reductions: focal partial + local root count
    fred[threadIdx.x] = fsum;
    ired[threadIdx.x] = rc;
    __syncthreads();
    for (int s = 128; s > 0; s >>= 1) {
        if (threadIdx.x < s) {
            fred[threadIdx.x] += fred[threadIdx.x + s];
            ired[threadIdx.x] += ired[threadIdx.x + s];
        }
        __syncthreads();
    }
    if (threadIdx.x == 0) {
        if (v < 4 && fred[0] != 0.0f) atomicAdd(acc, fred[0]);
        if (ired[0]) atomicAdd(&rootcnt[v], ired[0]);
    }
}

// ---------------------------------------------------------------------------
// Phase 2: one THREAD per boundary edge (792 blocks x 256 per volume; blocks
// never straddle faces since PLANE % 256 == 0). Per-block LDS dedup of
// root-pairs; path-compressed finds; union events counted and accumulated.
__global__ __launch_bounds__(256) void ccl_boundary(int* __restrict__ Lg,
                                                    int* __restrict__ events,
                                                    int vbase) {
    __shared__ unsigned long long ht[HT_SIZE];
    __shared__ int ered[256];
    for (int i = threadIdx.x; i < HT_SIZE; i += 256) ht[i] = ~0ull;
    __syncthreads();

    int tid  = blockIdx.x * 256 + threadIdx.x;   // < BOUND_VOX
    int vloc = blockIdx.y;
    int* Lv = Lg + (size_t)vloc * N_VOX;

    int ev = 0;
    {
        int face = tid / PLANE;                  // 0..21
        int e    = tid % PLANE;
        int j, jn;
        if (face < NBPLANES) {                   // w-faces: w in {8,...,88}
            int h = e / 96, d = e % 96;
            int w = (face + 1) * TW;
            j  = h * PLANE + w * 96 + d;
            jn = j - 96;
        } else {                                 // h-faces: h in {8,...,88}
            int w = e / 96, d = e % 96;
            int h = (face - NBPLANES + 1) * TH;
            j  = h * PLANE + w * 96 + d;
            jn = j - PLANE;
        }
        int a = Lv[j], b = Lv[jn];
        if (a >= 0 && b >= 0) {                  // both foreground
            a = find_root_compress(Lv, a);
            b = find_root_compress(Lv, b);
            if (a != b) {
                int rmin = a < b ? a : b;
                int rmax = a < b ? b : a;
                unsigned long long key = ((unsigned long long)rmin << 20) | (unsigned)rmax;
                unsigned long long hsh = (key ^ (key >> 29)) * 0x9E3779B97F4A7C15ull;
                unsigned slot = (unsigned)(hsh >> 43) & (HT_SIZE - 1);
                bool do_merge = false;
                for (int pr = 0; pr < HT_SIZE; pr++) {
                    unsigned long long prev = atomicCAS(&ht[slot], ~0ull, key);
                    if (prev == ~0ull) { do_merge = true; break; }   // inserted
                    if (prev == key)   { break; }                    // duplicate
                    slot = (slot + 1) & (HT_SIZE - 1);
                    if (pr == HT_SIZE - 1) do_merge = true;          // full: merge anyway
                }
                if (do_merge) ev = merge_count(Lv, rmin, rmax);
            }
        }
    }

    ered[threadIdx.x] = ev;
    __syncthreads();
    for (int s = 128; s > 0; s >>= 1) {
        if (threadIdx.x < s) ered[threadIdx.x] += ered[threadIdx.x + s];
        __syncthreads();
    }
    if (threadIdx.x == 0 && ered[0]) atomicAdd(&events[vbase + vloc], ered[0]);
}

// ---------------------------------------------------------------------------
// components[v] = rootcnt[v] - events[v]
__global__ void finalize_kernel(const float* __restrict__ acc,
                                const int* __restrict__ rootcnt,
                                const int* __restrict__ events,
                                float* __restrict__ out) {
    float focal = acc[0] / (float)NEL;
    float c[NVOL];
    for (int v = 0; v < NVOL; v++) c[v] = (float)(rootcnt[v] - events[v]);
    float dp0 = 0.5f * (c[0] + c[2]);
    float dp1 = 0.5f * (c[1] + c[3]);
    float dt0 = 0.5f * (c[4] + c[6]);
    float dt1 = 0.5f * (c[5] + c[7]);
    float topo = 0.5f * (fabsf(dp0 - dt0) + fabsf(dp1 - dt1));
    out[0] = focal + 0.1f * topo;
}

// ---------------------------------------------------------------------------
extern "C" void kernel_launch(void* const* d_in, const int* in_sizes, int n_in,
                              void* d_out, int out_size, void* d_ws, size_t ws_size,
                              hipStream_t stream) {
    const float* pred = (const float*)d_in[0];
    const float* targ = (const float*)d_in[1];
    float* out = (float*)d_out;

    // ws layout: [0] float acc; [64..95] int rootcnt[8]; [128..159] int
    // events[8]; [256..) labels
    float* acc     = (float*)d_ws;
    int*   rootcnt = (int*)((char*)d_ws + 64);
    int*   events  = (int*)((char*)d_ws + 128);
    int*   labels  = (int*)((char*)d_ws + 256);

    size_t avail_ints = (ws_size > 256) ? (ws_size - 256) / 4 : 0;
    int vols_per_pass = (int)(avail_ints / N_VOX);
    if (vols_per_pass > NVOL) vols_per_pass = NVOL;
    if (vols_per_pass < 1) vols_per_pass = 1;

    hipMemsetAsync(d_ws, 0, 256, stream);

    for (int vbase = 0; vbase < NVOL; vbase += vols_per_pass) {
        int nv = NVOL - vbase;
        if (nv > vols_per_pass) nv = vols_per_pass;
        dim3 tgrid(TILES_W * TILES_H, nv);
        ccl_local<<<tgrid, dim3(256), 0, stream>>>(pred, targ, labels, rootcnt, acc, vbase);
        dim3 bgrid(BOUND_VOX / 256, nv);
        ccl_boundary<<<bgrid, dim3(256), 0, stream>>>(labels, events, vbase);
    }

    finalize_kernel<<<1, 1, 0, stream>>>(acc, rootcnt, events, out);
}

// Round 6
// 220.242 us; speedup vs baseline: 1.6326x; 1.3559x over previous
//
#include <hip/hip_runtime.h>
#include <math.h>

#define N_VOX (96*96*96)        // 884736 voxels per volume
#define NVOL 8                  // 4 pred + 4 target volumes
#define NEL (4*N_VOX)           // 3538944 elements in pred/target
#define PLANE (96*96)           // 9216

// tile geometry for local CCL: full d-span x TW x TH
#define TW 8
#define TH 8
#define TILES_W 12
#define TILES_H 12
#define TILE_VOX (96*TW*TH)     // 6144
#define TILE_WORDS (TILE_VOX/32) // 192 (rows are 3-word aligned: 96 bits)

#define NBPLANES 11             // interior tile boundaries per axis
#define BOUND_VOX (2*NBPLANES*PLANE)    // 202752 edges/volume; 792*256 exactly
#define HT_SIZE 512             // per-block LDS dedup entries (4 KB)

// ---------------------------------------------------------------------------
// find with path compression on GLOBAL labels. Writes via atomicMin only ->
// labels stay monotonically decreasing (the invariant correctness rests on).
__device__ __forceinline__ int find_root_compress(int* __restrict__ L, int x) {
    int r = x;
    int p = L[r];
    while (p != r) { r = p; p = L[r]; }
    if (r != x) atomicMin(&L[x], r);
    return r;
}

// atomicMin union-find merge; returns # destroyed self-loops (union events).
// Each root destruction is observed exactly once (atomicMin returns old),
// so summing gives exactly (#initial roots - #final roots).
__device__ __forceinline__ int merge_count(int* __restrict__ L, int l1, int l2) {
    int ev = 0;
    while (l1 != l2) {
        if (l1 < l2) { int t = l1; l1 = l2; l2 = t; }   // l1 > l2
        int l3 = atomicMin(&L[l1], l2);
        if (l3 == l1) { ev++; l1 = l2; }
        else l1 = l3;
    }
    return ev;
}

// merge on LDS labels (links only run-start slots)
__device__ __forceinline__ void merge_local(int* lab, int l1, int l2) {
    while (l1 != l2 && l1 != lab[l1]) l1 = lab[l1];
    while (l1 != l2 && l2 != lab[l2]) l2 = lab[l2];
    while (l1 != l2) {
        if (l1 < l2) { int t = l1; l1 = l2; l2 = t; }
        int l3 = atomicMin(&lab[l1], l2);
        l1 = (l3 == l1) ? l2 : l3;
    }
}

// start index of the consecutive-fg d-run containing fg voxel i (d = i%96).
// Rows are 96 bits = exactly 3 aligned words in fm.
__device__ __forceinline__ int run_start(const unsigned* fm, int i, int d) {
    int rowb = (i - d) >> 5;            // first word of this row
    int k = d >> 5, bit = d & 31;
    unsigned below = bit ? (~fm[rowb + k] & ((1u << bit) - 1)) : 0u;
    int z = -1;                          // highest zero-bit position < d
    if (below) z = (k << 5) + 31 - __builtin_clz(below);
    else if (k > 0) {
        unsigned n1 = ~fm[rowb + k - 1];
        if (n1) z = ((k - 1) << 5) + 31 - __builtin_clz(n1);
        else if (k > 1) {
            unsigned n0 = ~fm[rowb];
            if (n0) z = 31 - __builtin_clz(n0);
        }
    }
    return (i - d) + z + 1;
}

// ---------------------------------------------------------------------------
// Phase 1: run-based per-tile CCL in LDS. fg as bit array (ballot); labels
// only meaningful at run-start slots; w/h merges only at overlap-segment
// starts. Fuses focal partial (pred volumes) and local root count.
__global__ __launch_bounds__(256) void ccl_local(const float* __restrict__ pred,
                                                 const float* __restrict__ targ,
                                                 int* __restrict__ Lg,
                                                 int* __restrict__ rootcnt,
                                                 float* __restrict__ acc,
                                                 int vbase) {
    __shared__ int lab[TILE_VOX];            // 24 KB
    __shared__ unsigned fm[TILE_WORDS];      // 768 B fg bit array
    __shared__ float fred[256];
    __shared__ int   ired[256];

    int vloc = blockIdx.y;
    int v = vbase + vloc;
    int tile = blockIdx.x;                   // 0..143
    int w0 = (tile % TILES_W) * TW;
    int h0 = (tile / TILES_W) * TH;
    int tbase = h0 * PLANE + w0 * 96;        // global index of tile origin
    int* Lvg = Lg + (size_t)vloc * N_VOX;

    // ---- load: fg bits via ballot; focal partial for pred volumes ----
    float fsum = 0.0f;
    for (int it = 0; it < TILE_VOX / 256; it++) {
        int i = it * 256 + threadIdx.x;
        int lh = i / 768;                    // i = lh*768 + lw*96 + d
        int j = tbase + i + lh * 8448;       // global voxel index
        bool f;
        if (v < 4) {
            float xv = pred[(size_t)v * N_VOX + j];
            float tv = targ[(size_t)v * N_VOX + j];
            float p  = 1.0f / (1.0f + expf(-xv));
            f = p > 0.5f;
            float pt  = (tv == 1.0f) ? p : 1.0f - p;
            float sp  = fmaxf(xv, 0.0f) + log1pf(expf(-fabsf(xv)));
            float bce = sp - xv * tv;
            float at  = (tv == 1.0f) ? 0.25f : 0.75f;
            float om  = 1.0f - pt;
            fsum += at * om * om * bce;
        } else {
            f = targ[(size_t)(v - 4) * N_VOX + j] > 0.5f;
        }
        unsigned long long bal = __ballot(f);
        if ((threadIdx.x & 63) == 0) {       // i is 64-aligned for lane 0
            fm[i >> 5]       = (unsigned)bal;
            fm[(i >> 5) + 1] = (unsigned)(bal >> 32);
        }
        lab[i] = i;
    }
    __syncthreads();

    // ---- merge: word-level overlap-segment starts, w then h direction ----
    // w-dir tasks: lh(8) x lw(7) x k(3) = 168 ; h-dir: lh(7) x lw(8) x k(3) = 168
    for (int t = threadIdx.x; t < 336; t += 256) {
        bool wdir = t < 168;
        int tt = wdir ? t : t - 168;
        int lh, lw, k;
        if (wdir) { lh = tt / 21; int rem = tt % 21; lw = rem / 3; k = rem % 3; }
        else      { lh = tt / 24; int rem = tt % 24; lw = rem / 3; k = rem % 3; }
        int wb = (lh * 8 + lw) * 3 + k;
        int nb = wb + (wdir ? 3 : 24);       // +96 or +768 in bit space
        unsigned ov = fm[wb] & fm[nb];
        if (!ov) continue;
        unsigned carry = (k > 0) ? ((fm[wb - 1] & fm[nb - 1]) >> 31) : 0u;
        unsigned starts = ov & ~((ov << 1) | carry);
        int base_i = wb << 5;
        int dir = wdir ? 96 : 768;
        while (starts) {
            int b = __builtin_ctz(starts);
            starts &= starts - 1;
            int i = base_i + b;
            int d = (k << 5) + b;
            merge_local(lab, run_start(fm, i, d), run_start(fm, i + dir, d));
        }
    }
    __syncthreads();

    // ---- flatten run-start slots to final root; count roots ----
    int rc = 0;
    for (int t = threadIdx.x; t < TILE_WORDS; t += 256) {
        unsigned m = fm[t];
        if (!m) continue;
        unsigned carry = (t % 3) ? (fm[t - 1] >> 31) : 0u;
        unsigned starts = m & ~((m << 1) | carry);   // run starts in this word
        int base_i = t << 5;
        while (starts) {
            int b = __builtin_ctz(starts); starts &= starts - 1;
            int i = base_i + b;
            int r = i;
            while (lab[r] != r) r = lab[r];
            if (r == i) rc++;
            lab[i] = r;                      // single writer per slot
        }
    }
    __syncthreads();

    // ---- overwrite run-start slots with GLOBAL root index (own slots only) --
    for (int t = threadIdx.x; t < TILE_WORDS; t += 256) {
        unsigned m = fm[t];
        if (!m) continue;
        unsigned carry = (t % 3) ? (fm[t - 1] >> 31) : 0u;
        unsigned starts = m & ~((m << 1) | carry);
        int base_i = t << 5;
        while (starts) {
            int b = __builtin_ctz(starts); starts &= starts - 1;
            int i = base_i + b;
            int r = lab[i];                  // own slot: no race
            lab[i] = tbase + r + (r / 768) * 8448;
        }
    }
    __syncthreads();

    // ---- resolve + store, int4-vectorized (rows are 4-aligned: 96%4==0) ----
    for (int t = threadIdx.x; t < TILE_VOX / 4; t += 256) {
        int row = t / 24;                    // 24 int4 groups per row
        int d4  = (t % 24) << 2;
        int i0  = row * 96 + d4;
        unsigned mw = fm[(i0 >> 5)];         // all 4 bits in one word (32%4==0)
        int vals[4];
        bool prevf = false;
        for (int q = 0; q < 4; q++) {
            int dd = d4 + q;
            bool f = (mw >> (dd & 31)) & 1;
            if (f) {
                if (prevf) vals[q] = vals[q - 1];      // same run
                else       vals[q] = lab[run_start(fm, i0 + q, dd)];
            } else vals[q] = -1;
            prevf = f;
        }
        int lh = row >> 3;
        int j0 = tbase + i0 + lh * 8448;
        *(int4*)(Lvg + j0) = make_int4(vals[0], vals[1], vals[2], vals[3]);
    }

    // ---- block reductions: focal partial + local root count ----
    fred[threadIdx.x] = fsum;
    ired[threadIdx.x] = rc;
    __syncthreads();
    for (int s = 128; s > 0; s >>= 1) {
        if (threadIdx.x < s) {
            fred[threadIdx.x] += fred[threadIdx.x + s];
            ired[threadIdx.x] += ired[threadIdx.x + s];
        }
        __syncthreads();
    }
    if (threadIdx.x == 0) {
        if (v < 4 && fred[0] != 0.0f) atomicAdd(acc, fred[0]);
        if (ired[0]) atomicAdd(&rootcnt[v], ired[0]);
    }
}

// ---------------------------------------------------------------------------
// Phase 2: one thread per boundary edge. An edge is processed only if it
// STARTS a both-fg overlap segment along d (exact d-dedup, before any global
// find); then raw-label-pair LDS dedup; then path-compressed find + merge
// with union-event counting.
__global__ __launch_bounds__(256) void ccl_boundary(int* __restrict__ Lg,
                                                    int* __restrict__ events,
                                                    int vbase) {
    __shared__ unsigned long long ht[HT_SIZE];
    __shared__ int ered[256];
    for (int i = threadIdx.x; i < HT_SIZE; i += 256) ht[i] = ~0ull;
    __syncthreads();

    int tid  = blockIdx.x * 256 + threadIdx.x;   // < BOUND_VOX
    int vloc = blockIdx.y;
    int* Lv = Lg + (size_t)vloc * N_VOX;

    int ev = 0;
    {
        int face = tid / PLANE;                  // 0..21
        int e    = tid % PLANE;
        int hw   = e / 96, d = e % 96;
        int j, jn;
        if (face < NBPLANES) {                   // w-faces: w in {8,...,88}
            j  = hw * PLANE + (face + 1) * TW * 96 + d;
            jn = j - 96;
        } else {                                 // h-faces: h in {8,...,88}
            j  = (face - NBPLANES + 1) * TH * PLANE + hw * 96 + d;
            jn = j - PLANE;
        }
        int a = Lv[j], b = Lv[jn];
        if (a >= 0 && b >= 0) {
            bool start = (d == 0) || (Lv[j - 1] < 0) || (Lv[jn - 1] < 0);
            if (start) {
                int rmin = a < b ? a : b;
                int rmax = a < b ? b : a;
                unsigned long long key = ((unsigned long long)rmin << 20) | (unsigned)rmax;
                unsigned long long hsh = (key ^ (key >> 29)) * 0x9E3779B97F4A7C15ull;
                unsigned slot = (unsigned)(hsh >> 43) & (HT_SIZE - 1);
                bool do_merge = false;
                for (int pr = 0; pr < HT_SIZE; pr++) {
                    unsigned long long prev = atomicCAS(&ht[slot], ~0ull, key);
                    if (prev == ~0ull) { do_merge = true; break; }
                    if (prev == key)   { break; }
                    slot = (slot + 1) & (HT_SIZE - 1);
                    if (pr == HT_SIZE - 1) do_merge = true;
                }
                if (do_merge) {
                    int ra = find_root_compress(Lv, rmin);
                    int rb = find_root_compress(Lv, rmax);
                    if (ra != rb) ev = merge_count(Lv, ra, rb);
                }
            }
        }
    }

    ered[threadIdx.x] = ev;
    __syncthreads();
    for (int s = 128; s > 0; s >>= 1) {
        if (threadIdx.x < s) ered[threadIdx.x] += ered[threadIdx.x + s];
        __syncthreads();
    }
    if (threadIdx.x == 0 && ered[0]) atomicAdd(&events[vbase + vloc], ered[0]);
}

// ---------------------------------------------------------------------------
// components[v] = rootcnt[v] - events[v]
__global__ void finalize_kernel(const float* __restrict__ acc,
                                const int* __restrict__ rootcnt,
                                const int* __restrict__ events,
                                float* __restrict__ out) {
    float focal = acc[0] / (float)NEL;
    float c[NVOL];
    for (int v = 0; v < NVOL; v++) c[v] = (float)(rootcnt[v] - events[v]);
    float dp0 = 0.5f * (c[0] + c[2]);
    float dp1 = 0.5f * (c[1] + c[3]);
    float dt0 = 0.5f * (c[4] + c[6]);
    float dt1 = 0.5f * (c[5] + c[7]);
    float topo = 0.5f * (fabsf(dp0 - dt0) + fabsf(dp1 - dt1));
    out[0] = focal + 0.1f * topo;
}

// ---------------------------------------------------------------------------
extern "C" void kernel_launch(void* const* d_in, const int* in_sizes, int n_in,
                              void* d_out, int out_size, void* d_ws, size_t ws_size,
                              hipStream_t stream) {
    const float* pred = (const float*)d_in[0];
    const float* targ = (const float*)d_in[1];
    float* out = (float*)d_out;

    // ws: [0] float acc; [64..] int rootcnt[8]; [128..] int events[8]; [256..) labels
    float* acc     = (float*)d_ws;
    int*   rootcnt = (int*)((char*)d_ws + 64);
    int*   events  = (int*)((char*)d_ws + 128);
    int*   labels  = (int*)((char*)d_ws + 256);

    size_t avail_ints = (ws_size > 256) ? (ws_size - 256) / 4 : 0;
    int vols_per_pass = (int)(avail_ints / N_VOX);
    if (vols_per_pass > NVOL) vols_per_pass = NVOL;
    if (vols_per_pass < 1) vols_per_pass = 1;

    hipMemsetAsync(d_ws, 0, 256, stream);

    for (int vbase = 0; vbase < NVOL; vbase += vols_per_pass) {
        int nv = NVOL - vbase;
        if (nv > vols_per_pass) nv = vols_per_pass;
        dim3 tgrid(TILES_W * TILES_H, nv);
        ccl_local<<<tgrid, dim3(256), 0, stream>>>(pred, targ, labels, rootcnt, acc, vbase);
        dim3 bgrid(BOUND_VOX / 256, nv);
        ccl_boundary<<<bgrid, dim3(256), 0, stream>>>(labels, events, vbase);
    }

    finalize_kernel<<<1, 1, 0, stream>>>(acc, rootcnt, events, out);
}

// Round 7
// 211.220 us; speedup vs baseline: 1.7023x; 1.0427x over previous
//
#include <hip/hip_runtime.h>
#include <math.h>

#define N_VOX (96*96*96)        // 884736 voxels per volume
#define NVOL 8                  // 4 pred + 4 target volumes
#define NEL (4*N_VOX)           // 3538944 elements in pred/target
#define PLANE (96*96)           // 9216

// tile geometry for local CCL: full d-span x TW x TH
#define TW 8
#define TH 8
#define TILES_W 12
#define TILES_H 12
#define TILE_VOX (96*TW*TH)     // 6144
#define TILE_WORDS (TILE_VOX/32) // 192 (rows are 3-word aligned: 96 bits)

#define NBPLANES 11             // interior tile boundaries per axis
#define BOUND_VOX (2*NBPLANES*PLANE)    // 202752 edges/volume; 792*256 exactly
#define HT_SIZE 512             // per-block LDS dedup entries (4 KB)
#define MAX_PROBES 32           // bounded probing; overflow -> merge anyway

// ---------------------------------------------------------------------------
// find with path compression on GLOBAL labels. Writes via atomicMin only ->
// labels stay monotonically decreasing (the invariant correctness rests on).
__device__ __forceinline__ int find_root_compress(int* __restrict__ L, int x) {
    int r = x;
    int p = L[r];
    while (p != r) { r = p; p = L[r]; }
    if (r != x) atomicMin(&L[x], r);
    return r;
}

// atomicMin union-find merge; returns # destroyed self-loops (union events).
// Each root destruction is observed exactly once (atomicMin returns old),
// so summing gives exactly (#initial roots - #final roots).
__device__ __forceinline__ int merge_count(int* __restrict__ L, int l1, int l2) {
    int ev = 0;
    while (l1 != l2) {
        if (l1 < l2) { int t = l1; l1 = l2; l2 = t; }   // l1 > l2
        int l3 = atomicMin(&L[l1], l2);
        if (l3 == l1) { ev++; l1 = l2; }
        else l1 = l3;
    }
    return ev;
}

// merge on LDS labels (links only run-start slots)
__device__ __forceinline__ void merge_local(int* lab, int l1, int l2) {
    while (l1 != l2 && l1 != lab[l1]) l1 = lab[l1];
    while (l1 != l2 && l2 != lab[l2]) l2 = lab[l2];
    while (l1 != l2) {
        if (l1 < l2) { int t = l1; l1 = l2; l2 = t; }
        int l3 = atomicMin(&lab[l1], l2);
        l1 = (l3 == l1) ? l2 : l3;
    }
}

// start index of the consecutive-fg d-run containing fg voxel i (d = i%96).
// Rows are 96 bits = exactly 3 aligned words in fm.
__device__ __forceinline__ int run_start(const unsigned* fm, int i, int d) {
    int rowb = (i - d) >> 5;            // first word of this row
    int k = d >> 5, bit = d & 31;
    unsigned below = bit ? (~fm[rowb + k] & ((1u << bit) - 1)) : 0u;
    int z = -1;                          // highest zero-bit position < d
    if (below) z = (k << 5) + 31 - __builtin_clz(below);
    else if (k > 0) {
        unsigned n1 = ~fm[rowb + k - 1];
        if (n1) z = ((k - 1) << 5) + 31 - __builtin_clz(n1);
        else if (k > 1) {
            unsigned n0 = ~fm[rowb];
            if (n0) z = 31 - __builtin_clz(n0);
        }
    }
    return (i - d) + z + 1;
}

// ---------------------------------------------------------------------------
// Phase 1: run-based per-tile CCL in LDS. fg as bit array (ballot); labels
// only meaningful at run-start slots; w/h merges only at overlap-segment
// starts. Fuses focal partial (pred volumes) and local root count.
__global__ __launch_bounds__(256) void ccl_local(const float* __restrict__ pred,
                                                 const float* __restrict__ targ,
                                                 int* __restrict__ Lg,
                                                 int* __restrict__ rootcnt,
                                                 float* __restrict__ acc,
                                                 int vbase) {
    __shared__ int lab[TILE_VOX];            // 24 KB
    __shared__ unsigned fm[TILE_WORDS];      // 768 B fg bit array
    __shared__ float fred[256];
    __shared__ int   ired[256];

    int vloc = blockIdx.y;
    int v = vbase + vloc;
    int tile = blockIdx.x;                   // 0..143
    int w0 = (tile % TILES_W) * TW;
    int h0 = (tile / TILES_W) * TH;
    int tbase = h0 * PLANE + w0 * 96;        // global index of tile origin
    int* Lvg = Lg + (size_t)vloc * N_VOX;

    // ---- load: fg bits via ballot; fast focal partial for pred volumes ----
    // focal identity: bce = softplus(x) - x*t = softplus(m), pt = sigmoid(-m),
    // 1-pt = sigmoid(m), with m = (t==1) ? -x : x. So
    // term = alpha_t * sigmoid(m)^2 * softplus(m): one exp + one log.
    float fsum = 0.0f;
    for (int it = 0; it < TILE_VOX / 256; it++) {
        int i = it * 256 + threadIdx.x;
        int lh = i / 768;                    // i = lh*768 + lw*96 + d
        int j = tbase + i + lh * 8448;       // global voxel index
        bool f;
        if (v < 4) {
            float xv = pred[(size_t)v * N_VOX + j];
            float tv = targ[(size_t)v * N_VOX + j];
            f = xv > 0.0f;                   // sigmoid(x)>0.5 <=> x>0
            float m   = (tv == 1.0f) ? -xv : xv;
            float at  = (tv == 1.0f) ? 0.25f : 0.75f;
            float e   = __expf(-fabsf(m));       // exp(-|m|) in (0,1]
            float inv = 1.0f / (1.0f + e);
            float sig = inv * ((m >= 0.0f) ? 1.0f : e);   // sigmoid(m)
            float sp  = fmaxf(m, 0.0f) + __logf(1.0f + e); // softplus(m)
            fsum += at * sig * sig * sp;
        } else {
            f = targ[(size_t)(v - 4) * N_VOX + j] > 0.5f;
        }
        unsigned long long bal = __ballot(f);
        if ((threadIdx.x & 63) == 0) {       // i is 64-aligned for lane 0
            fm[i >> 5]       = (unsigned)bal;
            fm[(i >> 5) + 1] = (unsigned)(bal >> 32);
        }
        lab[i] = i;
    }
    __syncthreads();

    // ---- merge: word-level overlap-segment starts, w then h direction ----
    // w-dir tasks: lh(8) x lw(7) x k(3) = 168 ; h-dir: lh(7) x lw(8) x k(3) = 168
    for (int t = threadIdx.x; t < 336; t += 256) {
        bool wdir = t < 168;
        int tt = wdir ? t : t - 168;
        int lh, lw, k;
        if (wdir) { lh = tt / 21; int rem = tt % 21; lw = rem / 3; k = rem % 3; }
        else      { lh = tt / 24; int rem = tt % 24; lw = rem / 3; k = rem % 3; }
        int wb = (lh * 8 + lw) * 3 + k;
        int nb = wb + (wdir ? 3 : 24);       // +96 or +768 in bit space
        unsigned ov = fm[wb] & fm[nb];
        if (!ov) continue;
        unsigned carry = (k > 0) ? ((fm[wb - 1] & fm[nb - 1]) >> 31) : 0u;
        unsigned starts = ov & ~((ov << 1) | carry);
        int base_i = wb << 5;
        int dir = wdir ? 96 : 768;
        while (starts) {
            int b = __builtin_ctz(starts);
            starts &= starts - 1;
            int i = base_i + b;
            int d = (k << 5) + b;
            merge_local(lab, run_start(fm, i, d), run_start(fm, i + dir, d));
        }
    }
    __syncthreads();

    // ---- flatten + globalize in ONE pass: each run-start owner walks to the
    // root and writes enc(globalroot) = ~g (negative) into its own slot.
    // Walkers hitting an already-finalized slot (negative) stop there; racing
    // with the owner is benign (both derive the identical global root).
    int rc = 0;
    for (int t = threadIdx.x; t < TILE_WORDS; t += 256) {
        unsigned m = fm[t];
        if (!m) continue;
        unsigned carry = (t % 3) ? (fm[t - 1] >> 31) : 0u;
        unsigned starts = m & ~((m << 1) | carry);   // run starts in this word
        int base_i = t << 5;
        while (starts) {
            int b = __builtin_ctz(starts); starts &= starts - 1;
            int i = base_i + b;
            int r = i;
            int p = lab[r];
            while (p >= 0 && p != r) { r = p; p = lab[r]; }
            int g;
            if (p < 0) g = p;                        // finalized downstream
            else {                                   // p == r: raw root
                if (r == i) rc++;
                g = ~(tbase + r + (r / 768) * 8448); // encode global root
            }
            lab[i] = g;                              // own slot: single writer
        }
    }
    __syncthreads();

    // ---- resolve + store, int4-vectorized (rows are 4-aligned: 96%4==0) ----
    for (int t = threadIdx.x; t < TILE_VOX / 4; t += 256) {
        int row = t / 24;                    // 24 int4 groups per row
        int d4  = (t % 24) << 2;
        int i0  = row * 96 + d4;
        unsigned mw = fm[(i0 >> 5)];         // all 4 bits in one word (32%4==0)
        int vals[4];
        bool prevf = false;
        for (int q = 0; q < 4; q++) {
            int dd = d4 + q;
            bool f = (mw >> (dd & 31)) & 1;
            if (f) {
                if (prevf) vals[q] = vals[q - 1];      // same run
                else       vals[q] = ~lab[run_start(fm, i0 + q, dd)]; // decode
            } else vals[q] = -1;
            prevf = f;
        }
        int lh = row >> 3;
        int j0 = tbase + i0 + lh * 8448;
        *(int4*)(Lvg + j0) = make_int4(vals[0], vals[1], vals[2], vals[3]);
    }

    // ---- block reductions: focal partial + local root count ----
    fred[threadIdx.x] = fsum;
    ired[threadIdx.x] = rc;
    __syncthreads();
    for (int s = 128; s > 0; s >>= 1) {
        if (threadIdx.x < s) {
            fred[threadIdx.x] += fred[threadIdx.x + s];
            ired[threadIdx.x] += ired[threadIdx.x + s];
        }
        __syncthreads();
    }
    if (threadIdx.x == 0) {
        if (v < 4 && fred[0] != 0.0f) atomicAdd(acc, fred[0]);
        if (ired[0]) atomicAdd(&rootcnt[v], ired[0]);
    }
}

// ---------------------------------------------------------------------------
// Phase 2: one thread per boundary edge. Edge processed only if it STARTS a
// both-fg overlap segment along d (exact d-dedup). Then RESOLVE ROOTS FIRST
// (path-compressed finds; ~95% of pairs become equal and skip everything),
// then LDS-dedup the resolved pair with bounded probing, then merge with
// union-event counting.
__global__ __launch_bounds__(256) void ccl_boundary(int* __restrict__ Lg,
                                                    int* __restrict__ events,
                                                    int vbase) {
    __shared__ unsigned long long ht[HT_SIZE];
    __shared__ int ered[256];
    for (int i = threadIdx.x; i < HT_SIZE; i += 256) ht[i] = ~0ull;
    __syncthreads();

    int tid  = blockIdx.x * 256 + threadIdx.x;   // < BOUND_VOX
    int vloc = blockIdx.y;
    int* Lv = Lg + (size_t)vloc * N_VOX;

    int ev = 0;
    {
        int face = tid / PLANE;                  // 0..21
        int e    = tid % PLANE;
        int hw   = e / 96, d = e % 96;
        int j, jn;
        if (face < NBPLANES) {                   // w-faces: w in {8,...,88}
            j  = hw * PLANE + (face + 1) * TW * 96 + d;
            jn = j - 96;
        } else {                                 // h-faces: h in {8,...,88}
            j  = (face - NBPLANES + 1) * TH * PLANE + hw * 96 + d;
            jn = j - PLANE;
        }
        int a = Lv[j], b = Lv[jn];
        if (a >= 0 && b >= 0) {
            bool start = (d == 0) || (Lv[j - 1] < 0) || (Lv[jn - 1] < 0);
            if (start) {
                a = find_root_compress(Lv, a);
                b = find_root_compress(Lv, b);
                if (a != b) {
                    int rmin = a < b ? a : b;
                    int rmax = a < b ? b : a;
                    unsigned long long key = ((unsigned long long)rmin << 20) | (unsigned)rmax;
                    unsigned long long hsh = (key ^ (key >> 29)) * 0x9E3779B97F4A7C15ull;
                    unsigned slot = (unsigned)(hsh >> 43) & (HT_SIZE - 1);
                    bool do_merge = false;
                    for (int pr = 0; pr < MAX_PROBES; pr++) {
                        unsigned long long prev = atomicCAS(&ht[slot], ~0ull, key);
                        if (prev == ~0ull) { do_merge = true; break; }   // inserted
                        if (prev == key)   { break; }                    // duplicate
                        slot = (slot + 1) & (HT_SIZE - 1);
                        if (pr == MAX_PROBES - 1) do_merge = true;       // give up: merge
                    }
                    if (do_merge) ev = merge_count(Lv, rmin, rmax);
                }
            }
        }
    }

    ered[threadIdx.x] = ev;
    __syncthreads();
    for (int s = 128; s > 0; s >>= 1) {
        if (threadIdx.x < s) ered[threadIdx.x] += ered[threadIdx.x + s];
        __syncthreads();
    }
    if (threadIdx.x == 0 && ered[0]) atomicAdd(&events[vbase + vloc], ered[0]);
}

// ---------------------------------------------------------------------------
// components[v] = rootcnt[v] - events[v]
__global__ void finalize_kernel(const float* __restrict__ acc,
                                const int* __restrict__ rootcnt,
                                const int* __restrict__ events,
                                float* __restrict__ out) {
    float focal = acc[0] / (float)NEL;
    float c[NVOL];
    for (int v = 0; v < NVOL; v++) c[v] = (float)(rootcnt[v] - events[v]);
    float dp0 = 0.5f * (c[0] + c[2]);
    float dp1 = 0.5f * (c[1] + c[3]);
    float dt0 = 0.5f * (c[4] + c[6]);
    float dt1 = 0.5f * (c[5] + c[7]);
    float topo = 0.5f * (fabsf(dp0 - dt0) + fabsf(dp1 - dt1));
    out[0] = focal + 0.1f * topo;
}

// ---------------------------------------------------------------------------
extern "C" void kernel_launch(void* const* d_in, const int* in_sizes, int n_in,
                              void* d_out, int out_size, void* d_ws, size_t ws_size,
                              hipStream_t stream) {
    const float* pred = (const float*)d_in[0];
    const float* targ = (const float*)d_in[1];
    float* out = (float*)d_out;

    // ws: [0] float acc; [64..] int rootcnt[8]; [128..] int events[8]; [256..) labels
    float* acc     = (float*)d_ws;
    int*   rootcnt = (int*)((char*)d_ws + 64);
    int*   events  = (int*)((char*)d_ws + 128);
    int*   labels  = (int*)((char*)d_ws + 256);

    size_t avail_ints = (ws_size > 256) ? (ws_size - 256) / 4 : 0;
    int vols_per_pass = (int)(avail_ints / N_VOX);
    if (vols_per_pass > NVOL) vols_per_pass = NVOL;
    if (vols_per_pass < 1) vols_per_pass = 1;

    hipMemsetAsync(d_ws, 0, 256, stream);

    for (int vbase = 0; vbase < NVOL; vbase += vols_per_pass) {
        int nv = NVOL - vbase;
        if (nv > vols_per_pass) nv = vols_per_pass;
        dim3 tgrid(TILES_W * TILES_H, nv);
        ccl_local<<<tgrid, dim3(256), 0, stream>>>(pred, targ, labels, rootcnt, acc, vbase);
        dim3 bgrid(BOUND_VOX / 256, nv);
        ccl_boundary<<<bgrid, dim3(256), 0, stream>>>(labels, events, vbase);
    }

    finalize_kernel<<<1, 1, 0, stream>>>(acc, rootcnt, events, out);
}

// Round 8
// 208.841 us; speedup vs baseline: 1.7217x; 1.0114x over previous
//
#include <hip/hip_runtime.h>
#include <math.h>

#define N_VOX (96*96*96)        // 884736 voxels per volume
#define NVOL 8                  // 4 pred + 4 target volumes
#define NEL (4*N_VOX)           // 3538944 elements in pred/target
#define PLANE (96*96)           // 9216

// tile geometry for local CCL: full d-span x TW x TH
#define TW 8
#define TH 8
#define TILES_W 12
#define TILES_H 12
#define TILE_VOX (96*TW*TH)     // 6144
#define TILE_WORDS (TILE_VOX/32) // 192

#define NBPLANES 11             // interior tile boundaries per axis
#define BOUND_VOX (2*NBPLANES*PLANE)      // 202752 edges/volume = 792*256
#define FACES_PER_VOL (2*2*NBPLANES*PLANE) // 405504 ints (w+h, 2 sides each)
#define HT_SIZE 512             // per-block LDS dedup entries (4 KB)
#define MAX_PROBES 32

// ---------------------------------------------------------------------------
// find with path compression on GLOBAL labels (root slots only). Writes via
// atomicMin only -> labels stay monotonically decreasing.
__device__ __forceinline__ int find_root_compress(int* __restrict__ L, int x) {
    int r = x;
    int p = L[r];
    while (p != r) { r = p; p = L[r]; }
    if (r != x) atomicMin(&L[x], r);
    return r;
}

// atomicMin union-find merge; returns # destroyed self-loops (union events).
__device__ __forceinline__ int merge_count(int* __restrict__ L, int l1, int l2) {
    int ev = 0;
    while (l1 != l2) {
        if (l1 < l2) { int t = l1; l1 = l2; l2 = t; }   // l1 > l2
        int l3 = atomicMin(&L[l1], l2);
        if (l3 == l1) { ev++; l1 = l2; }
        else l1 = l3;
    }
    return ev;
}

// merge on LDS labels (links only run-start slots)
__device__ __forceinline__ void merge_local(int* lab, int l1, int l2) {
    while (l1 != l2 && l1 != lab[l1]) l1 = lab[l1];
    while (l1 != l2 && l2 != lab[l2]) l2 = lab[l2];
    while (l1 != l2) {
        if (l1 < l2) { int t = l1; l1 = l2; l2 = t; }
        int l3 = atomicMin(&lab[l1], l2);
        l1 = (l3 == l1) ? l2 : l3;
    }
}

// start index of the consecutive-fg d-run containing fg voxel i (d = i%96).
__device__ __forceinline__ int run_start(const unsigned* fm, int i, int d) {
    int rowb = (i - d) >> 5;
    int k = d >> 5, bit = d & 31;
    unsigned below = bit ? (~fm[rowb + k] & ((1u << bit) - 1)) : 0u;
    int z = -1;
    if (below) z = (k << 5) + 31 - __builtin_clz(below);
    else if (k > 0) {
        unsigned n1 = ~fm[rowb + k - 1];
        if (n1) z = ((k - 1) << 5) + 31 - __builtin_clz(n1);
        else if (k > 1) {
            unsigned n0 = ~fm[rowb];
            if (n0) z = 31 - __builtin_clz(n0);
        }
    }
    return (i - d) + z + 1;
}

// ---------------------------------------------------------------------------
// Phase 1: run-based per-tile CCL in LDS. Outputs ONLY:
//   (a) compact face arrays (resolved global-root labels, -1 = bg) for the
//       4 interior-adjacent tile faces, int4-coalesced;
//   (b) sparse root-slot init Lg[g] = g for each tile root;
//   (c) rootcnt[v] += #tile roots; acc += focal partial (pred volumes).
// The full per-voxel label volume is never materialized.
__global__ __launch_bounds__(256) void ccl_local(const float* __restrict__ pred,
                                                 const float* __restrict__ targ,
                                                 int* __restrict__ Lg,
                                                 int* __restrict__ faces,
                                                 int* __restrict__ rootcnt,
                                                 float* __restrict__ acc,
                                                 int vbase) {
    __shared__ int lab[TILE_VOX];            // 24 KB
    __shared__ unsigned fm[TILE_WORDS];      // 768 B fg bit array
    __shared__ float fws[4];
    __shared__ int   iws[4];

    int vloc = blockIdx.y;
    int v = vbase + vloc;
    int tile = blockIdx.x;                   // 0..143
    int tw = tile % TILES_W, th = tile / TILES_W;
    int w0 = tw * TW, h0 = th * TH;
    int tbase = h0 * PLANE + w0 * 96;        // global index of tile origin
    int* Lvg = Lg + (size_t)vloc * N_VOX;
    int* Fw  = faces + (size_t)vloc * FACES_PER_VOL;   // [b][side][h*96+d]
    int* Fh  = Fw + 2 * NBPLANES * PLANE;              // [b][side][w*96+d]

    // ---- load: fg bits via ballot; fast focal partial for pred volumes ----
    float fsum = 0.0f;
    for (int it = 0; it < TILE_VOX / 256; it++) {
        int i = it * 256 + threadIdx.x;
        int lh = i / 768;                    // i = lh*768 + lw*96 + d
        int j = tbase + i + lh * 8448;       // global voxel index
        bool f;
        if (v < 4) {
            float xv = pred[(size_t)v * N_VOX + j];
            float tv = targ[(size_t)v * N_VOX + j];
            f = xv > 0.0f;                   // sigmoid(x)>0.5 <=> x>0
            float m   = (tv == 1.0f) ? -xv : xv;
            float at  = (tv == 1.0f) ? 0.25f : 0.75f;
            float e   = __expf(-fabsf(m));
            float inv = 1.0f / (1.0f + e);
            float sig = inv * ((m >= 0.0f) ? 1.0f : e);    // sigmoid(m)
            float sp  = fmaxf(m, 0.0f) + __logf(1.0f + e); // softplus(m)
            fsum += at * sig * sig * sp;
        } else {
            f = targ[(size_t)(v - 4) * N_VOX + j] > 0.5f;
        }
        unsigned long long bal = __ballot(f);
        if ((threadIdx.x & 63) == 0) {
            fm[i >> 5]       = (unsigned)bal;
            fm[(i >> 5) + 1] = (unsigned)(bal >> 32);
        }
        lab[i] = i;
    }
    __syncthreads();

    // ---- merge: word-level overlap-segment starts, w then h direction ----
    for (int t = threadIdx.x; t < 336; t += 256) {
        bool wdir = t < 168;
        int tt = wdir ? t : t - 168;
        int lh, lw, k;
        if (wdir) { lh = tt / 21; int rem = tt % 21; lw = rem / 3; k = rem % 3; }
        else      { lh = tt / 24; int rem = tt % 24; lw = rem / 3; k = rem % 3; }
        int wb = (lh * 8 + lw) * 3 + k;
        int nb = wb + (wdir ? 3 : 24);
        unsigned ov = fm[wb] & fm[nb];
        if (!ov) continue;
        unsigned carry = (k > 0) ? ((fm[wb - 1] & fm[nb - 1]) >> 31) : 0u;
        unsigned starts = ov & ~((ov << 1) | carry);
        int base_i = wb << 5;
        int dir = wdir ? 96 : 768;
        while (starts) {
            int b = __builtin_ctz(starts);
            starts &= starts - 1;
            int i = base_i + b;
            int d = (k << 5) + b;
            merge_local(lab, run_start(fm, i, d), run_start(fm, i + dir, d));
        }
    }
    __syncthreads();

    // ---- flatten + globalize + sparse root init ----
    int rc = 0;
    for (int t = threadIdx.x; t < TILE_WORDS; t += 256) {
        unsigned m = fm[t];
        if (!m) continue;
        unsigned carry = (t % 3) ? (fm[t - 1] >> 31) : 0u;
        unsigned starts = m & ~((m << 1) | carry);
        int base_i = t << 5;
        while (starts) {
            int b = __builtin_ctz(starts); starts &= starts - 1;
            int i = base_i + b;
            int r = i;
            int p = lab[r];
            while (p >= 0 && p != r) { r = p; p = lab[r]; }
            int g;
            if (p < 0) g = p;                        // finalized downstream
            else {                                   // p == r: raw root
                int gr = tbase + r + (r / 768) * 8448;
                g = ~gr;
                if (r == i) { rc++; Lvg[gr] = gr; }  // sparse root-slot init
            }
            lab[i] = g;                              // own slot: single writer
        }
    }
    __syncthreads();

    // ---- resolve + store the 4 interior-adjacent faces (int4 groups) ----
    // face f: 0 = lw=0 (side B of w-boundary tw-1), 1 = lw=7 (side A of tw),
    //         2 = lh=0 (side B of h-boundary th-1), 3 = lh=7 (side A of th)
    for (int t = threadIdx.x; t < 768; t += 256) {
        int f  = t / 192;
        int g  = t % 192;
        int u  = g / 24;                     // row within face (lh or lw)
        int d4 = (g % 24) * 4;
        int i0; int* dst;
        if (f == 0) {
            if (tw == 0) continue;
            i0  = u * 768 + d4;
            dst = Fw + ((tw - 1) * 2 + 1) * PLANE + (h0 + u) * 96 + d4;
        } else if (f == 1) {
            if (tw == TILES_W - 1) continue;
            i0  = u * 768 + 7 * 96 + d4;
            dst = Fw + (tw * 2) * PLANE + (h0 + u) * 96 + d4;
        } else if (f == 2) {
            if (th == 0) continue;
            i0  = u * 96 + d4;
            dst = Fh + ((th - 1) * 2 + 1) * PLANE + (w0 + u) * 96 + d4;
        } else {
            if (th == TILES_H - 1) continue;
            i0  = 7 * 768 + u * 96 + d4;
            dst = Fh + (th * 2) * PLANE + (w0 + u) * 96 + d4;
        }
        unsigned mw = fm[i0 >> 5];           // bits d4..d4+3 in one word
        int vals[4];
        bool prevf = false;
        for (int q = 0; q < 4; q++) {
            bool fb = (mw >> ((d4 & 31) + q)) & 1;
            if (fb) vals[q] = prevf ? vals[q - 1]
                                    : ~lab[run_start(fm, i0 + q, d4 + q)];
            else vals[q] = -1;
            prevf = fb;
        }
        *(int4*)dst = make_int4(vals[0], vals[1], vals[2], vals[3]);
    }

    // ---- wave-shuffle reductions: focal partial + local root count ----
    for (int off = 32; off; off >>= 1) {
        fsum += __shfl_down(fsum, off, 64);
        rc   += __shfl_down(rc,   off, 64);
    }
    int wid = threadIdx.x >> 6;
    if ((threadIdx.x & 63) == 0) { fws[wid] = fsum; iws[wid] = rc; }
    __syncthreads();
    if (threadIdx.x == 0) {
        float ft = fws[0] + fws[1] + fws[2] + fws[3];
        int   rt = iws[0] + iws[1] + iws[2] + iws[3];
        if (v < 4 && ft != 0.0f) atomicAdd(acc, ft);
        if (rt) atomicAdd(&rootcnt[v], rt);
    }
}

// ---------------------------------------------------------------------------
// Phase 2: one thread per boundary edge, reading ONLY the compact face
// arrays (coalesced) + the hot root slots. Edge processed only at overlap-
// segment starts along d; resolve roots first; LDS-dedup resolved pairs;
// merge with union-event counting.
__global__ __launch_bounds__(256) void ccl_boundary(int* __restrict__ Lg,
                                                    const int* __restrict__ faces,
                                                    int* __restrict__ events,
                                                    int vbase) {
    __shared__ unsigned long long ht[HT_SIZE];
    __shared__ int evacc;
    for (int i = threadIdx.x; i < HT_SIZE; i += 256) ht[i] = ~0ull;
    if (threadIdx.x == 0) evacc = 0;
    __syncthreads();

    int tid  = blockIdx.x * 256 + threadIdx.x;   // < BOUND_VOX
    int vloc = blockIdx.y;
    int* Lv = Lg + (size_t)vloc * N_VOX;
    const int* F = faces + (size_t)vloc * FACES_PER_VOL;

    int face = tid / PLANE;                      // 0..21
    int e    = tid % PLANE;
    const int* A;
    const int* B;
    if (face < NBPLANES) {
        A = F + (face * 2) * PLANE;
        B = F + (face * 2 + 1) * PLANE;
    } else {
        const int* Fh = F + 2 * NBPLANES * PLANE;
        int b = face - NBPLANES;
        A = Fh + (b * 2) * PLANE;
        B = Fh + (b * 2 + 1) * PLANE;
    }

    int a = A[e], b2 = B[e];
    int ev = 0;
    if (a >= 0 && b2 >= 0) {
        int d = e % 96;
        bool start = (d == 0) || (A[e - 1] < 0) || (B[e - 1] < 0);
        if (start) {
            a  = find_root_compress(Lv, a);
            b2 = find_root_compress(Lv, b2);
            if (a != b2) {
                int rmin = a < b2 ? a : b2;
                int rmax = a < b2 ? b2 : a;
                unsigned long long key = ((unsigned long long)rmin << 20) | (unsigned)rmax;
                unsigned long long hsh = (key ^ (key >> 29)) * 0x9E3779B97F4A7C15ull;
                unsigned slot = (unsigned)(hsh >> 43) & (HT_SIZE - 1);
                bool do_merge = false;
                for (int pr = 0; pr < MAX_PROBES; pr++) {
                    unsigned long long prev = atomicCAS(&ht[slot], ~0ull, key);
                    if (prev == ~0ull) { do_merge = true; break; }
                    if (prev == key)   { break; }
                    slot = (slot + 1) & (HT_SIZE - 1);
                    if (pr == MAX_PROBES - 1) do_merge = true;
                }
                if (do_merge) ev = merge_count(Lv, rmin, rmax);
            }
        }
    }
    if (ev) atomicAdd(&evacc, ev);
    __syncthreads();
    if (threadIdx.x == 0 && evacc) atomicAdd(&events[vbase + vloc], evacc);
}

// ---------------------------------------------------------------------------
// components[v] = rootcnt[v] - events[v]
__global__ void finalize_kernel(const float* __restrict__ acc,
                                const int* __restrict__ rootcnt,
                                const int* __restrict__ events,
                                float* __restrict__ out) {
    float focal = acc[0] / (float)NEL;
    float c[NVOL];
    for (int v = 0; v < NVOL; v++) c[v] = (float)(rootcnt[v] - events[v]);
    float dp0 = 0.5f * (c[0] + c[2]);
    float dp1 = 0.5f * (c[1] + c[3]);
    float dt0 = 0.5f * (c[4] + c[6]);
    float dt1 = 0.5f * (c[5] + c[7]);
    float topo = 0.5f * (fabsf(dp0 - dt0) + fabsf(dp1 - dt1));
    out[0] = focal + 0.1f * topo;
}

// ---------------------------------------------------------------------------
extern "C" void kernel_launch(void* const* d_in, const int* in_sizes, int n_in,
                              void* d_out, int out_size, void* d_ws, size_t ws_size,
                              hipStream_t stream) {
    const float* pred = (const float*)d_in[0];
    const float* targ = (const float*)d_in[1];
    float* out = (float*)d_out;

    // ws: [0] float acc; [64..] int rootcnt[8]; [128..] int events[8];
    // [256..) labels[vp*N_VOX] then faces[vp*FACES_PER_VOL]
    float* acc     = (float*)d_ws;
    int*   rootcnt = (int*)((char*)d_ws + 64);
    int*   events  = (int*)((char*)d_ws + 128);
    int*   labels  = (int*)((char*)d_ws + 256);

    size_t avail_ints = (ws_size > 256) ? (ws_size - 256) / 4 : 0;
    int vols_per_pass = (int)(avail_ints / (N_VOX + FACES_PER_VOL));
    if (vols_per_pass > NVOL) vols_per_pass = NVOL;
    if (vols_per_pass < 1) vols_per_pass = 1;
    int* faces = labels + (size_t)vols_per_pass * N_VOX;

    hipMemsetAsync(d_ws, 0, 256, stream);

    for (int vbase = 0; vbase < NVOL; vbase += vols_per_pass) {
        int nv = NVOL - vbase;
        if (nv > vols_per_pass) nv = vols_per_pass;
        dim3 tgrid(TILES_W * TILES_H, nv);
        ccl_local<<<tgrid, dim3(256), 0, stream>>>(pred, targ, labels, faces,
                                                   rootcnt, acc, vbase);
        dim3 bgrid(BOUND_VOX / 256, nv);
        ccl_boundary<<<bgrid, dim3(256), 0, stream>>>(labels, faces, events, vbase);
    }

    finalize_kernel<<<1, 1, 0, stream>>>(acc, rootcnt, events, out);
}